// Round 1
// baseline (2306.745 us; speedup 1.0000x reference)
//
#include <hip/hip_runtime.h>
#include <hip/hip_bf16.h>

// Problem: y[m][n] = sum_k x[m][k] * (wq[n][k] * scale[n]) + bias[n]
//   M = B*S = 8192, K = 4096, N = 16384. out fp32.
// Strategy: pre-convert x (fp32->bf16, ~2^-9 rel err) and wq (int8-in-int32 ->
// bf16, EXACT since |v|<=127 fits bf16's 8-bit significand) into d_ws, then a
// bf16 MFMA GEMM (m97-class 128x128 tile, BK=64, global_load_lds staging),
// scale/bias applied in the fp32 epilogue.

#define M_TOT 8192
#define N_TOT 16384
#define K_TOT 4096

typedef __attribute__((ext_vector_type(8))) short bf16x8;
typedef __attribute__((ext_vector_type(4))) float f32x4;

// ---------------- conversion kernels (memory-bound, grid-stride) -----------

__global__ __launch_bounds__(256) void cvt_f32_bf16(const float* __restrict__ in,
                                                    unsigned short* __restrict__ out,
                                                    long n) {
    const long stride = (long)gridDim.x * blockDim.x * 8;
    for (long i = ((long)blockIdx.x * blockDim.x + threadIdx.x) * 8; i < n; i += stride) {
        float4 a = *(const float4*)(in + i);
        float4 b = *(const float4*)(in + i + 4);
        union { bf16x8 v; __hip_bfloat16 h[8]; } u;
        u.h[0] = __float2bfloat16(a.x);
        u.h[1] = __float2bfloat16(a.y);
        u.h[2] = __float2bfloat16(a.z);
        u.h[3] = __float2bfloat16(a.w);
        u.h[4] = __float2bfloat16(b.x);
        u.h[5] = __float2bfloat16(b.y);
        u.h[6] = __float2bfloat16(b.z);
        u.h[7] = __float2bfloat16(b.w);
        *(bf16x8*)(out + i) = u.v;
    }
}

__global__ __launch_bounds__(256) void cvt_i32_bf16(const int* __restrict__ in,
                                                    unsigned short* __restrict__ out,
                                                    long n) {
    const long stride = (long)gridDim.x * blockDim.x * 8;
    for (long i = ((long)blockIdx.x * blockDim.x + threadIdx.x) * 8; i < n; i += stride) {
        int4 a = *(const int4*)(in + i);
        int4 b = *(const int4*)(in + i + 4);
        union { bf16x8 v; __hip_bfloat16 h[8]; } u;
        u.h[0] = __float2bfloat16((float)a.x);   // exact: |v| <= 127
        u.h[1] = __float2bfloat16((float)a.y);
        u.h[2] = __float2bfloat16((float)a.z);
        u.h[3] = __float2bfloat16((float)a.w);
        u.h[4] = __float2bfloat16((float)b.x);
        u.h[5] = __float2bfloat16((float)b.y);
        u.h[6] = __float2bfloat16((float)b.z);
        u.h[7] = __float2bfloat16((float)b.w);
        *(bf16x8*)(out + i) = u.v;
    }
}

// ---------------- main GEMM (m97-class 128x128 tile) -----------------------

__device__ __forceinline__ void async_copy16(const unsigned short* g, unsigned short* l) {
    __builtin_amdgcn_global_load_lds(
        (const __attribute__((address_space(1))) unsigned int*)g,
        (__attribute__((address_space(3))) unsigned int*)l,
        16, 0, 0);
}

__global__ __launch_bounds__(256) void gemm_bf16(const unsigned short* __restrict__ Xb,
                                                 const unsigned short* __restrict__ Wb,
                                                 const float* __restrict__ scale,
                                                 const float* __restrict__ bias,
                                                 float* __restrict__ out) {
    // Block: 256 threads = 4 waves in a 2x2 grid; each wave owns a 64x64
    // output sub-tile = 4x4 fragments of 16x16 (mfma_f32_16x16x32_bf16).
    __shared__ unsigned short As[128 * 64];   // [row][k] bf16, 16 KiB
    __shared__ unsigned short Bs[128 * 64];   // [n-row][k] bf16, 16 KiB

    const int tid  = threadIdx.x;
    const int wave = tid >> 6;
    const int lane = tid & 63;
    const int bn   = blockIdx.x;     // N tile (0..127)
    const int bm   = blockIdx.y;     // M tile (0..63)
    const int wm   = wave >> 1;      // 0..1
    const int wn   = wave & 1;       // 0..1
    const int lr   = lane >> 3;      // staging: row within 8-row group
    const int lc   = lane & 7;       // staging: 16B chunk within 128B row

    f32x4 acc[4][4];
#pragma unroll
    for (int i = 0; i < 4; ++i)
#pragma unroll
        for (int j = 0; j < 4; ++j)
            acc[i][j] = (f32x4){0.f, 0.f, 0.f, 0.f};

    // Per-lane global staging bases. Each wave stages rows [wave*32, wave*32+32)
    // of the 128-row tile via 4 issues of 8 rows x 128 B (lane l -> row l/8,
    // 16B chunk l%8). LDS dest is linear (wave-uniform base + lane*16).
    const unsigned short* aSrc = Xb + ((long)bm * 128 + wave * 32 + lr) * K_TOT + lc * 8;
    const unsigned short* bSrc = Wb + ((long)bn * 128 + wave * 32 + lr) * K_TOT + lc * 8;

    for (int kt = 0; kt < K_TOT; kt += 64) {
        __syncthreads();   // previous tile fully consumed
#pragma unroll
        for (int j = 0; j < 4; ++j) {
            async_copy16(aSrc + (long)j * 8 * K_TOT + kt, &As[(wave * 32 + j * 8) * 64]);
            async_copy16(bSrc + (long)j * 8 * K_TOT + kt, &Bs[(wave * 32 + j * 8) * 64]);
        }
        __syncthreads();   // compiler drains vmcnt(0) before s_barrier

        bf16x8 af[2][4], bfr[2][4];
#pragma unroll
        for (int ks = 0; ks < 2; ++ks) {
#pragma unroll
            for (int f = 0; f < 4; ++f) {
                af[ks][f]  = *(const bf16x8*)&As[(wm * 64 + f * 16 + (lane & 15)) * 64 + ks * 32 + (lane >> 4) * 8];
                bfr[ks][f] = *(const bf16x8*)&Bs[(wn * 64 + f * 16 + (lane & 15)) * 64 + ks * 32 + (lane >> 4) * 8];
            }
        }
#pragma unroll
        for (int ks = 0; ks < 2; ++ks)
#pragma unroll
            for (int mf = 0; mf < 4; ++mf)
#pragma unroll
                for (int nf = 0; nf < 4; ++nf)
                    acc[mf][nf] = __builtin_amdgcn_mfma_f32_16x16x32_bf16(
                        af[ks][mf], bfr[ks][nf], acc[mf][nf], 0, 0, 0);
    }

    // Epilogue: C/D layout for 16x16x32: col = lane&15, row = (lane>>4)*4 + r.
    const int col0 = bn * 128 + wn * 64;
    const int row0 = bm * 128 + wm * 64;
#pragma unroll
    for (int nf = 0; nf < 4; ++nf) {
        const int gn = col0 + nf * 16 + (lane & 15);
        const float sc = scale[gn];
        const float bi = bias[gn];
#pragma unroll
        for (int mf = 0; mf < 4; ++mf) {
            const int gm = row0 + mf * 16 + ((lane >> 4) << 2);
#pragma unroll
            for (int r = 0; r < 4; ++r) {
                out[(long)(gm + r) * N_TOT + gn] = acc[mf][nf][r] * sc + bi;
            }
        }
    }
}

// ---------------- fallback (only if d_ws is too small) ---------------------

__global__ __launch_bounds__(1024) void gemm_fallback(const float* __restrict__ x,
                                                      const int* __restrict__ wq,
                                                      const float* __restrict__ scale,
                                                      const float* __restrict__ bias,
                                                      float* __restrict__ out) {
    __shared__ float xs[32][33];
    __shared__ float ws[32][33];
    const int tx = threadIdx.x, ty = threadIdx.y;
    const int gm = blockIdx.y * 32 + ty;
    const int gn = blockIdx.x * 32 + tx;
    float acc = 0.f;
    for (int kt = 0; kt < K_TOT; kt += 32) {
        xs[ty][tx] = x[(long)gm * K_TOT + kt + tx];
        ws[ty][tx] = (float)wq[(long)(blockIdx.x * 32 + ty) * K_TOT + kt + tx];
        __syncthreads();
#pragma unroll
        for (int kk = 0; kk < 32; ++kk) acc += xs[ty][kk] * ws[tx][kk];
        __syncthreads();
    }
    out[(long)gm * N_TOT + gn] = acc * scale[gn] + bias[gn];
}

// ---------------- launch ---------------------------------------------------

extern "C" void kernel_launch(void* const* d_in, const int* in_sizes, int n_in,
                              void* d_out, int out_size, void* d_ws, size_t ws_size,
                              hipStream_t stream) {
    const float* x     = (const float*)d_in[0];
    const int*   wq    = (const int*)d_in[1];
    const float* scale = (const float*)d_in[2];
    const float* bias  = (const float*)d_in[3];
    float*       out   = (float*)d_out;

    const size_t xElems = (size_t)M_TOT * K_TOT;                 // 33.5M
    const size_t wElems = (size_t)N_TOT * K_TOT;                 // 67.1M
    const size_t needed = (xElems + wElems) * sizeof(unsigned short);  // 192 MiB

    if (ws_size >= needed) {
        unsigned short* Xb = (unsigned short*)d_ws;
        unsigned short* Wb = Xb + xElems;
        cvt_f32_bf16<<<2048, 256, 0, stream>>>(x, Xb, (long)xElems);
        cvt_i32_bf16<<<2048, 256, 0, stream>>>(wq, Wb, (long)wElems);
        dim3 grid(N_TOT / 128, M_TOT / 128);   // 128 x 64 = 8192 blocks
        gemm_bf16<<<grid, 256, 0, stream>>>(Xb, Wb, scale, bias, out);
    } else {
        dim3 grid(N_TOT / 32, M_TOT / 32);
        gemm_fallback<<<grid, dim3(32, 32), 0, stream>>>(x, wq, scale, bias, out);
    }
}